// Round 1
// baseline (742.288 us; speedup 1.0000x reference)
//
#include <hip/hip_runtime.h>

#define N_NODES 100000
#define N_EDGES 1600000
#define IN_DIM 64
#define HID 128
#define N_GRAPHS 512
#define SCAN_NB 98  // ceil(100000/1024)

// ---------------- degree count ----------------
__global__ __launch_bounds__(256) void k_deg(const int* __restrict__ src, const int* __restrict__ dst,
                                             int* __restrict__ dego, int* __restrict__ degi) {
    int i = blockIdx.x * 256 + threadIdx.x;
    if (i < N_EDGES) {
        atomicAdd(&dego[src[i]], 1);
        atomicAdd(&degi[dst[i]], 1);
    }
}

// ---------------- rsqrt of clipped degrees ----------------
__global__ __launch_bounds__(256) void k_rs(const int* __restrict__ dego, const int* __restrict__ degi,
                                            float* __restrict__ rso, float* __restrict__ rsi) {
    int i = blockIdx.x * 256 + threadIdx.x;
    if (i < N_NODES) {
        rso[i] = 1.0f / sqrtf(fmaxf((float)dego[i], 1.0f));
        rsi[i] = 1.0f / sqrtf(fmaxf((float)degi[i], 1.0f));
    }
}

// ---------------- scan (3 kernels) for CSR row_ptr over deg_in ----------------
__global__ __launch_bounds__(256) void k_scan1(const int* __restrict__ deg, int* __restrict__ partial,
                                               int* __restrict__ bsums) {
    __shared__ int lds[256];
    int t = threadIdx.x, b = blockIdx.x;
    int base = b * 1024 + t * 4;
    int v0 = 0, v1 = 0, v2 = 0, v3 = 0;
    if (base + 3 < N_NODES) {
        v0 = deg[base]; v1 = deg[base + 1]; v2 = deg[base + 2]; v3 = deg[base + 3];
    } else {
        if (base < N_NODES) v0 = deg[base];
        if (base + 1 < N_NODES) v1 = deg[base + 1];
        if (base + 2 < N_NODES) v2 = deg[base + 2];
        if (base + 3 < N_NODES) v3 = deg[base + 3];
    }
    v1 += v0; v2 += v1; v3 += v2;  // thread-local inclusive
    lds[t] = v3;
    __syncthreads();
    for (int off = 1; off < 256; off <<= 1) {
        int x = (t >= off) ? lds[t - off] : 0;
        __syncthreads();
        lds[t] += x;
        __syncthreads();
    }
    int prev = (t > 0) ? lds[t - 1] : 0;
    if (base < N_NODES) partial[base] = v0 + prev;
    if (base + 1 < N_NODES) partial[base + 1] = v1 + prev;
    if (base + 2 < N_NODES) partial[base + 2] = v2 + prev;
    if (base + 3 < N_NODES) partial[base + 3] = v3 + prev;
    if (t == 255) bsums[b] = lds[255];
}

__global__ __launch_bounds__(128) void k_scan2(int* __restrict__ bsums) {
    __shared__ int l[128];
    int t = threadIdx.x;
    l[t] = (t < SCAN_NB) ? bsums[t] : 0;
    __syncthreads();
    for (int off = 1; off < 128; off <<= 1) {
        int v = (t >= off) ? l[t - off] : 0;
        __syncthreads();
        l[t] += v;
        __syncthreads();
    }
    if (t < SCAN_NB) bsums[t] = (t > 0) ? l[t - 1] : 0;  // exclusive block offsets
}

__global__ __launch_bounds__(256) void k_scan3(const int* __restrict__ partial, const int* __restrict__ bsums,
                                               const int* __restrict__ degi, int* __restrict__ rowp,
                                               int* __restrict__ cursor) {
    int i = blockIdx.x * 256 + threadIdx.x;
    if (i >= N_NODES) return;
    int incl = partial[i] + bsums[i >> 10];
    rowp[i + 1] = incl;
    cursor[i] = incl - degi[i];  // exclusive start
    if (i == 0) rowp[0] = 0;
}

// ---------------- scatter edge list into CSR ----------------
__global__ __launch_bounds__(256) void k_scatter(const int* __restrict__ src, const int* __restrict__ dst,
                                                 int* __restrict__ cursor, int* __restrict__ col) {
    int i = blockIdx.x * 256 + threadIdx.x;
    if (i < N_EDGES) {
        int d = dst[i];
        int p = atomicAdd(&cursor[d], 1);
        col[p] = src[i];
    }
}

// ---------------- xs = x * rs_out (pre-scale source features) ----------------
__global__ __launch_bounds__(256) void k_scale_x(const float4* __restrict__ x, const float* __restrict__ rso,
                                                 float4* __restrict__ xs) {
    int i = blockIdx.x * 256 + threadIdx.x;
    if (i < N_NODES * IN_DIM / 4) {
        float r = rso[i >> 4];  // 16 float4 per 64-float row
        float4 v = x[i];
        v.x *= r; v.y *= r; v.z *= r; v.w *= r;
        xs[i] = v;
    }
}

// ---------------- gather-sum aggregation, one wave per dst node ----------------
__global__ __launch_bounds__(256) void k_gather64(const float* __restrict__ h, const int* __restrict__ rowp,
                                                  const int* __restrict__ col, float* __restrict__ agg) {
    int wv = (blockIdx.x * 256 + threadIdx.x) >> 6;
    int lane = threadIdx.x & 63;
    if (wv >= N_NODES) return;
    int s = rowp[wv], e = rowp[wv + 1];
    float acc = 0.f;
    for (int i = s; i < e; ++i) {
        int c = col[i];
        acc += h[c * IN_DIM + lane];
    }
    agg[wv * IN_DIM + lane] = acc;
}

__global__ __launch_bounds__(256) void k_gather128(const float* __restrict__ h, const int* __restrict__ rowp,
                                                   const int* __restrict__ col, float* __restrict__ agg) {
    int wv = (blockIdx.x * 256 + threadIdx.x) >> 6;
    int lane = threadIdx.x & 63;
    if (wv >= N_NODES) return;
    int s = rowp[wv], e = rowp[wv + 1];
    const float2* hp = (const float2*)h;
    float ax = 0.f, ay = 0.f;
    for (int i = s; i < e; ++i) {
        int c = col[i];
        float2 v = hp[c * 64 + lane];
        ax += v.x; ay += v.y;
    }
    float2 o; o.x = ax; o.y = ay;
    ((float2*)agg)[wv * 64 + lane] = o;
}

// ---------------- tiled f32 matmul: out = epilogue(A @ W) ----------------
// A: [n, K], W: [K, 128]. out[n][j] = relu(dot * rs_in[n] + bias[j]) * (SCALE_OUT ? rs_out[n] : 1)
template <int K, bool SCALE_OUT>
__global__ __launch_bounds__(256) void k_mm(const float* __restrict__ A, const float* __restrict__ W,
                                            const float* __restrict__ bias, const float* __restrict__ rsi,
                                            const float* __restrict__ rso, float* __restrict__ out) {
    __shared__ float WL[32 * 128];   // one 32-row chunk of W
    __shared__ float aL[32][33];     // 32 nodes x 32 k (padded)
    const int t = threadIdx.x;
    const int jq = t & 31;           // covers columns jq*4 .. jq*4+3
    const int ns = t >> 5;           // node group: nodes ns*4 .. ns*4+3
    const int n0 = blockIdx.x * 32;
    float acc[4][4] = {};
    for (int kc = 0; kc < K; kc += 32) {
        const float4* Wg = (const float4*)(W + kc * 128);
        float4* WL4 = (float4*)WL;
#pragma unroll
        for (int u = 0; u < 4; ++u) WL4[t + 256 * u] = Wg[t + 256 * u];
        {
            int r = t >> 3, q = t & 7;
            int node = n0 + r;
            float4 v = make_float4(0.f, 0.f, 0.f, 0.f);
            if (node < N_NODES) v = *(const float4*)(A + node * K + kc + q * 4);
            aL[r][q * 4 + 0] = v.x; aL[r][q * 4 + 1] = v.y;
            aL[r][q * 4 + 2] = v.z; aL[r][q * 4 + 3] = v.w;
        }
        __syncthreads();
#pragma unroll
        for (int k = 0; k < 32; ++k) {
            float4 wv = ((const float4*)WL)[k * 32 + jq];
#pragma unroll
            for (int i = 0; i < 4; ++i) {
                float av = aL[ns * 4 + i][k];
                acc[i][0] += av * wv.x; acc[i][1] += av * wv.y;
                acc[i][2] += av * wv.z; acc[i][3] += av * wv.w;
            }
        }
        __syncthreads();
    }
#pragma unroll
    for (int i = 0; i < 4; ++i) {
        int node = n0 + ns * 4 + i;
        if (node >= N_NODES) continue;
        float ri = rsi[node];
        float ro = SCALE_OUT ? rso[node] : 1.0f;
        float4 bj = ((const float4*)bias)[jq];
        float4 o;
        o.x = fmaxf(acc[i][0] * ri + bj.x, 0.f) * ro;
        o.y = fmaxf(acc[i][1] * ri + bj.y, 0.f) * ro;
        o.z = fmaxf(acc[i][2] * ri + bj.z, 0.f) * ro;
        o.w = fmaxf(acc[i][3] * ri + bj.w, 0.f) * ro;
        *(float4*)(out + node * HID + jq * 4) = o;
    }
}

// ---------------- per-graph node ranges (graph_ids is sorted) ----------------
__global__ __launch_bounds__(256) void k_bounds(const int* __restrict__ gid, int* __restrict__ gstart) {
    int g = blockIdx.x * 256 + threadIdx.x;
    if (g > N_GRAPHS) return;
    int lo = 0, hi = N_NODES;
    while (lo < hi) {
        int mid = (lo + hi) >> 1;
        if (gid[mid] < g) lo = mid + 1; else hi = mid;
    }
    gstart[g] = lo;
}

// ---------------- mean-pool + 3-layer MLP head, one block per graph ----------------
__global__ __launch_bounds__(128) void k_pool_mlp(const float* __restrict__ h2, const int* __restrict__ gstart,
                                                  const float* __restrict__ Wc1, const float* __restrict__ bc1,
                                                  const float* __restrict__ Wc2, const float* __restrict__ bc2,
                                                  const float* __restrict__ Wc3, const float* __restrict__ bc3,
                                                  float* __restrict__ out) {
    int g = blockIdx.x, t = threadIdx.x;
    int s = gstart[g], e = gstart[g + 1];
    float acc = 0.f;
    for (int n = s; n < e; ++n) acc += h2[n * HID + t];
    float cnt = fmaxf((float)(e - s), 1.0f);
    __shared__ float buf[HID];
    __shared__ float red[2];
    buf[t] = acc / cnt;
    __syncthreads();
    float a = bc1[t];
#pragma unroll 8
    for (int k = 0; k < HID; ++k) a += buf[k] * Wc1[k * HID + t];
    a = fmaxf(a, 0.f);
    __syncthreads();
    buf[t] = a;
    __syncthreads();
    float b = bc2[t];
#pragma unroll 8
    for (int k = 0; k < HID; ++k) b += buf[k] * Wc2[k * HID + t];
    b = fmaxf(b, 0.f);
    float p = b * Wc3[t];
    for (int off = 32; off > 0; off >>= 1) p += __shfl_down(p, off, 64);
    if ((t & 63) == 0) red[t >> 6] = p;
    __syncthreads();
    if (t == 0) out[g] = red[0] + red[1] + bc3[0];
}

extern "C" void kernel_launch(void* const* d_in, const int* in_sizes, int n_in,
                              void* d_out, int out_size, void* d_ws, size_t ws_size,
                              hipStream_t stream) {
    const float* x   = (const float*)d_in[0];
    const int* esrc  = (const int*)d_in[1];
    const int* edst  = (const int*)d_in[2];
    const int* gid   = (const int*)d_in[3];
    const float* W1  = (const float*)d_in[4];
    const float* b1  = (const float*)d_in[5];
    const float* W2  = (const float*)d_in[6];
    const float* b2  = (const float*)d_in[7];
    const float* Wc1 = (const float*)d_in[8];
    const float* bc1 = (const float*)d_in[9];
    const float* Wc2 = (const float*)d_in[10];
    const float* bc2 = (const float*)d_in[11];
    const float* Wc3 = (const float*)d_in[12];
    const float* bc3 = (const float*)d_in[13];
    float* out = (float*)d_out;

    char* w = (char*)d_ws;
    size_t off = 0;
    auto alloc = [&](size_t bytes) -> char* {
        char* p = w + off;
        off += (bytes + 255) & ~(size_t)255;
        return p;
    };
    int* dego    = (int*)alloc((size_t)2 * N_NODES * 4);  // dego + degi contiguous for one memset
    int* degi    = dego + N_NODES;
    float* rso   = (float*)alloc((size_t)N_NODES * 4);
    float* rsi   = (float*)alloc((size_t)N_NODES * 4);
    int* rowp    = (int*)alloc((size_t)(N_NODES + 1) * 4);
    int* cursor  = (int*)alloc((size_t)N_NODES * 4);
    int* partial = (int*)alloc((size_t)N_NODES * 4);
    int* bsums   = (int*)alloc(1024);
    int* gstart  = (int*)alloc((size_t)(N_GRAPHS + 1) * 4);
    int* col     = (int*)alloc((size_t)N_EDGES * 4);
    float* R1    = (float*)alloc((size_t)N_NODES * HID * 4);  // xs | agg1, later agg2
    float* R2    = (float*)alloc((size_t)N_NODES * HID * 4);  // h1s, later h2
    float* xs   = R1;
    float* agg1 = R1 + (size_t)N_NODES * IN_DIM;
    float* agg2 = R1;
    float* h1s  = R2;
    float* h2   = R2;

    (void)in_sizes; (void)n_in; (void)out_size; (void)ws_size;

    hipMemsetAsync(dego, 0, (size_t)2 * N_NODES * 4, stream);

    const int EB = (N_EDGES + 255) / 256;   // 6250
    const int NB = (N_NODES + 255) / 256;   // 391

    k_deg<<<EB, 256, 0, stream>>>(esrc, edst, dego, degi);
    k_rs<<<NB, 256, 0, stream>>>(dego, degi, rso, rsi);
    k_scan1<<<SCAN_NB, 256, 0, stream>>>(degi, partial, bsums);
    k_scan2<<<1, 128, 0, stream>>>(bsums);
    k_scan3<<<NB, 256, 0, stream>>>(partial, bsums, degi, rowp, cursor);
    k_scatter<<<EB, 256, 0, stream>>>(esrc, edst, cursor, col);
    k_scale_x<<<(N_NODES * IN_DIM / 4 + 255) / 256, 256, 0, stream>>>((const float4*)x, rso, (float4*)xs);
    k_gather64<<<(N_NODES * 64 + 255) / 256, 256, 0, stream>>>(xs, rowp, col, agg1);
    k_mm<IN_DIM, true><<<(N_NODES + 31) / 32, 256, 0, stream>>>(agg1, W1, b1, rsi, rso, h1s);
    k_gather128<<<(N_NODES * 64 + 255) / 256, 256, 0, stream>>>(h1s, rowp, col, agg2);
    k_mm<HID, false><<<(N_NODES + 31) / 32, 256, 0, stream>>>(agg2, W2, b2, rsi, rso, h2);
    k_bounds<<<3, 256, 0, stream>>>(gid, gstart);
    k_pool_mlp<<<N_GRAPHS, 128, 0, stream>>>(h2, gstart, Wc1, bc1, Wc2, bc2, Wc3, bc3, out);
}

// Round 2
// 589.238 us; speedup vs baseline: 1.2597x; 1.2597x over previous
//
#include <hip/hip_runtime.h>

#define N_NODES 100000
#define N_EDGES 1600000
#define IN_DIM 64
#define HID 128
#define N_GRAPHS 512
#define SCAN_NB 98  // ceil(100000/1024)

// ---------------- degree count ----------------
__global__ __launch_bounds__(256) void k_deg(const int* __restrict__ src, const int* __restrict__ dst,
                                             int* __restrict__ dego, int* __restrict__ degi) {
    int i = blockIdx.x * 256 + threadIdx.x;
    if (i < N_EDGES) {
        atomicAdd(&dego[src[i]], 1);
        atomicAdd(&degi[dst[i]], 1);
    }
}

// ---------------- rsqrt of clipped degrees ----------------
__global__ __launch_bounds__(256) void k_rs(const int* __restrict__ dego, const int* __restrict__ degi,
                                            float* __restrict__ rso, float* __restrict__ rsi) {
    int i = blockIdx.x * 256 + threadIdx.x;
    if (i < N_NODES) {
        rso[i] = 1.0f / sqrtf(fmaxf((float)dego[i], 1.0f));
        rsi[i] = 1.0f / sqrtf(fmaxf((float)degi[i], 1.0f));
    }
}

// ---------------- scan (3 kernels) for CSR row_ptr over deg_in ----------------
__global__ __launch_bounds__(256) void k_scan1(const int* __restrict__ deg, int* __restrict__ partial,
                                               int* __restrict__ bsums) {
    __shared__ int lds[256];
    int t = threadIdx.x, b = blockIdx.x;
    int base = b * 1024 + t * 4;
    int v0 = 0, v1 = 0, v2 = 0, v3 = 0;
    if (base + 3 < N_NODES) {
        v0 = deg[base]; v1 = deg[base + 1]; v2 = deg[base + 2]; v3 = deg[base + 3];
    } else {
        if (base < N_NODES) v0 = deg[base];
        if (base + 1 < N_NODES) v1 = deg[base + 1];
        if (base + 2 < N_NODES) v2 = deg[base + 2];
        if (base + 3 < N_NODES) v3 = deg[base + 3];
    }
    v1 += v0; v2 += v1; v3 += v2;  // thread-local inclusive
    lds[t] = v3;
    __syncthreads();
    for (int off = 1; off < 256; off <<= 1) {
        int x = (t >= off) ? lds[t - off] : 0;
        __syncthreads();
        lds[t] += x;
        __syncthreads();
    }
    int prev = (t > 0) ? lds[t - 1] : 0;
    if (base < N_NODES) partial[base] = v0 + prev;
    if (base + 1 < N_NODES) partial[base + 1] = v1 + prev;
    if (base + 2 < N_NODES) partial[base + 2] = v2 + prev;
    if (base + 3 < N_NODES) partial[base + 3] = v3 + prev;
    if (t == 255) bsums[b] = lds[255];
}

__global__ __launch_bounds__(128) void k_scan2(int* __restrict__ bsums) {
    __shared__ int l[128];
    int t = threadIdx.x;
    l[t] = (t < SCAN_NB) ? bsums[t] : 0;
    __syncthreads();
    for (int off = 1; off < 128; off <<= 1) {
        int v = (t >= off) ? l[t - off] : 0;
        __syncthreads();
        l[t] += v;
        __syncthreads();
    }
    if (t < SCAN_NB) bsums[t] = (t > 0) ? l[t - 1] : 0;  // exclusive block offsets
}

__global__ __launch_bounds__(256) void k_scan3(const int* __restrict__ partial, const int* __restrict__ bsums,
                                               const int* __restrict__ degi, int* __restrict__ rowp,
                                               int* __restrict__ cursor) {
    int i = blockIdx.x * 256 + threadIdx.x;
    if (i >= N_NODES) return;
    int incl = partial[i] + bsums[i >> 10];
    rowp[i + 1] = incl;
    cursor[i] = incl - degi[i];  // exclusive start
    if (i == 0) rowp[0] = 0;
}

// ---------------- scatter edge list into CSR ----------------
__global__ __launch_bounds__(256) void k_scatter(const int* __restrict__ src, const int* __restrict__ dst,
                                                 int* __restrict__ cursor, int* __restrict__ col) {
    int i = blockIdx.x * 256 + threadIdx.x;
    if (i < N_EDGES) {
        int d = dst[i];
        int p = atomicAdd(&cursor[d], 1);
        col[p] = src[i];
    }
}

// ---------------- gather-sum aggregation (64-dim), rso scale fused ----------------
// One wave per dst node. 4 groups of 16 lanes; each group processes every 4th edge,
// lane loads float4 (16B) -> 4 concurrent row-loads, unroll x4 -> 16 in flight.
__global__ __launch_bounds__(256) void k_gather64(const float4* __restrict__ x4, const float* __restrict__ rso,
                                                  const int* __restrict__ rowp, const int* __restrict__ col,
                                                  float4* __restrict__ agg4) {
    int wv = (blockIdx.x * 256 + threadIdx.x) >> 6;
    if (wv >= N_NODES) return;
    int lane = threadIdx.x & 63;
    int grp = lane >> 4, li = lane & 15;
    int s = rowp[wv], e = rowp[wv + 1];
    float ax = 0.f, ay = 0.f, az = 0.f, aw = 0.f;
    int i = s + grp;
    for (; i + 12 < e; i += 16) {
        int c0 = col[i], c1 = col[i + 4], c2 = col[i + 8], c3 = col[i + 12];
        float4 v0 = x4[c0 * 16 + li];
        float4 v1 = x4[c1 * 16 + li];
        float4 v2 = x4[c2 * 16 + li];
        float4 v3 = x4[c3 * 16 + li];
        float r0 = rso[c0], r1 = rso[c1], r2 = rso[c2], r3 = rso[c3];
        ax = fmaf(r0, v0.x, ax); ay = fmaf(r0, v0.y, ay); az = fmaf(r0, v0.z, az); aw = fmaf(r0, v0.w, aw);
        ax = fmaf(r1, v1.x, ax); ay = fmaf(r1, v1.y, ay); az = fmaf(r1, v1.z, az); aw = fmaf(r1, v1.w, aw);
        ax = fmaf(r2, v2.x, ax); ay = fmaf(r2, v2.y, ay); az = fmaf(r2, v2.z, az); aw = fmaf(r2, v2.w, aw);
        ax = fmaf(r3, v3.x, ax); ay = fmaf(r3, v3.y, ay); az = fmaf(r3, v3.z, az); aw = fmaf(r3, v3.w, aw);
    }
    for (; i < e; i += 4) {
        int c = col[i];
        float4 v = x4[c * 16 + li];
        float r = rso[c];
        ax = fmaf(r, v.x, ax); ay = fmaf(r, v.y, ay); az = fmaf(r, v.z, az); aw = fmaf(r, v.w, aw);
    }
    // reduce across the 4 groups (lane bits 4 and 5)
    ax += __shfl_xor(ax, 16, 64); ay += __shfl_xor(ay, 16, 64);
    az += __shfl_xor(az, 16, 64); aw += __shfl_xor(aw, 16, 64);
    ax += __shfl_xor(ax, 32, 64); ay += __shfl_xor(ay, 32, 64);
    az += __shfl_xor(az, 32, 64); aw += __shfl_xor(aw, 32, 64);
    if (lane < 16) {
        float4 o; o.x = ax; o.y = ay; o.z = az; o.w = aw;
        agg4[wv * 16 + li] = o;
    }
}

// ---------------- gather-sum aggregation (128-dim) ----------------
// One wave per dst node. 2 groups of 32 lanes; lane loads float4 -> 2 concurrent
// row-loads, unroll x4 -> 8 in flight. Coalesced 512B row write from 32 lanes.
__global__ __launch_bounds__(256) void k_gather128(const float4* __restrict__ h4, const int* __restrict__ rowp,
                                                   const int* __restrict__ col, float4* __restrict__ agg4) {
    int wv = (blockIdx.x * 256 + threadIdx.x) >> 6;
    if (wv >= N_NODES) return;
    int lane = threadIdx.x & 63;
    int grp = lane >> 5, li = lane & 31;
    int s = rowp[wv], e = rowp[wv + 1];
    float ax = 0.f, ay = 0.f, az = 0.f, aw = 0.f;
    int i = s + grp;
    for (; i + 6 < e; i += 8) {
        int c0 = col[i], c1 = col[i + 2], c2 = col[i + 4], c3 = col[i + 6];
        float4 v0 = h4[c0 * 32 + li];
        float4 v1 = h4[c1 * 32 + li];
        float4 v2 = h4[c2 * 32 + li];
        float4 v3 = h4[c3 * 32 + li];
        ax += v0.x + v1.x + v2.x + v3.x;
        ay += v0.y + v1.y + v2.y + v3.y;
        az += v0.z + v1.z + v2.z + v3.z;
        aw += v0.w + v1.w + v2.w + v3.w;
    }
    for (; i < e; i += 2) {
        float4 v = h4[col[i] * 32 + li];
        ax += v.x; ay += v.y; az += v.z; aw += v.w;
    }
    // reduce across the 2 groups (lane bit 5)
    ax += __shfl_xor(ax, 32, 64); ay += __shfl_xor(ay, 32, 64);
    az += __shfl_xor(az, 32, 64); aw += __shfl_xor(aw, 32, 64);
    if (lane < 32) {
        float4 o; o.x = ax; o.y = ay; o.z = az; o.w = aw;
        agg4[wv * 32 + li] = o;
    }
}

// ---------------- tiled f32 matmul: out = epilogue(A @ W) ----------------
// A: [n, K], W: [K, 128]. out[n][j] = relu(dot * rs_in[n] + bias[j]) * (SCALE_OUT ? rs_out[n] : 1)
template <int K, bool SCALE_OUT>
__global__ __launch_bounds__(256) void k_mm(const float* __restrict__ A, const float* __restrict__ W,
                                            const float* __restrict__ bias, const float* __restrict__ rsi,
                                            const float* __restrict__ rso, float* __restrict__ out) {
    __shared__ float WL[32 * 128];   // one 32-row chunk of W
    __shared__ float aL[32][33];     // 32 nodes x 32 k (padded)
    const int t = threadIdx.x;
    const int jq = t & 31;           // covers columns jq*4 .. jq*4+3
    const int ns = t >> 5;           // node group: nodes ns*4 .. ns*4+3
    const int n0 = blockIdx.x * 32;
    float acc[4][4] = {};
    for (int kc = 0; kc < K; kc += 32) {
        const float4* Wg = (const float4*)(W + kc * 128);
        float4* WL4 = (float4*)WL;
#pragma unroll
        for (int u = 0; u < 4; ++u) WL4[t + 256 * u] = Wg[t + 256 * u];
        {
            int r = t >> 3, q = t & 7;
            int node = n0 + r;
            float4 v = make_float4(0.f, 0.f, 0.f, 0.f);
            if (node < N_NODES) v = *(const float4*)(A + node * K + kc + q * 4);
            aL[r][q * 4 + 0] = v.x; aL[r][q * 4 + 1] = v.y;
            aL[r][q * 4 + 2] = v.z; aL[r][q * 4 + 3] = v.w;
        }
        __syncthreads();
#pragma unroll
        for (int k = 0; k < 32; ++k) {
            float4 wv = ((const float4*)WL)[k * 32 + jq];
#pragma unroll
            for (int i = 0; i < 4; ++i) {
                float av = aL[ns * 4 + i][k];
                acc[i][0] += av * wv.x; acc[i][1] += av * wv.y;
                acc[i][2] += av * wv.z; acc[i][3] += av * wv.w;
            }
        }
        __syncthreads();
    }
#pragma unroll
    for (int i = 0; i < 4; ++i) {
        int node = n0 + ns * 4 + i;
        if (node >= N_NODES) continue;
        float ri = rsi[node];
        float ro = SCALE_OUT ? rso[node] : 1.0f;
        float4 bj = ((const float4*)bias)[jq];
        float4 o;
        o.x = fmaxf(acc[i][0] * ri + bj.x, 0.f) * ro;
        o.y = fmaxf(acc[i][1] * ri + bj.y, 0.f) * ro;
        o.z = fmaxf(acc[i][2] * ri + bj.z, 0.f) * ro;
        o.w = fmaxf(acc[i][3] * ri + bj.w, 0.f) * ro;
        *(float4*)(out + node * HID + jq * 4) = o;
    }
}

// ---------------- per-graph node ranges (graph_ids is sorted) ----------------
__global__ __launch_bounds__(256) void k_bounds(const int* __restrict__ gid, int* __restrict__ gstart) {
    int g = blockIdx.x * 256 + threadIdx.x;
    if (g > N_GRAPHS) return;
    int lo = 0, hi = N_NODES;
    while (lo < hi) {
        int mid = (lo + hi) >> 1;
        if (gid[mid] < g) lo = mid + 1; else hi = mid;
    }
    gstart[g] = lo;
}

// ---------------- mean-pool + 3-layer MLP head, one block per graph ----------------
__global__ __launch_bounds__(128) void k_pool_mlp(const float* __restrict__ h2, const int* __restrict__ gstart,
                                                  const float* __restrict__ Wc1, const float* __restrict__ bc1,
                                                  const float* __restrict__ Wc2, const float* __restrict__ bc2,
                                                  const float* __restrict__ Wc3, const float* __restrict__ bc3,
                                                  float* __restrict__ out) {
    int g = blockIdx.x, t = threadIdx.x;
    int s = gstart[g], e = gstart[g + 1];
    float acc = 0.f;
    for (int n = s; n < e; ++n) acc += h2[n * HID + t];
    float cnt = fmaxf((float)(e - s), 1.0f);
    __shared__ float buf[HID];
    __shared__ float red[2];
    buf[t] = acc / cnt;
    __syncthreads();
    float a = bc1[t];
#pragma unroll 8
    for (int k = 0; k < HID; ++k) a += buf[k] * Wc1[k * HID + t];
    a = fmaxf(a, 0.f);
    __syncthreads();
    buf[t] = a;
    __syncthreads();
    float b = bc2[t];
#pragma unroll 8
    for (int k = 0; k < HID; ++k) b += buf[k] * Wc2[k * HID + t];
    b = fmaxf(b, 0.f);
    float p = b * Wc3[t];
    for (int off = 32; off > 0; off >>= 1) p += __shfl_down(p, off, 64);
    if ((t & 63) == 0) red[t >> 6] = p;
    __syncthreads();
    if (t == 0) out[g] = red[0] + red[1] + bc3[0];
}

extern "C" void kernel_launch(void* const* d_in, const int* in_sizes, int n_in,
                              void* d_out, int out_size, void* d_ws, size_t ws_size,
                              hipStream_t stream) {
    const float* x   = (const float*)d_in[0];
    const int* esrc  = (const int*)d_in[1];
    const int* edst  = (const int*)d_in[2];
    const int* gid   = (const int*)d_in[3];
    const float* W1  = (const float*)d_in[4];
    const float* b1  = (const float*)d_in[5];
    const float* W2  = (const float*)d_in[6];
    const float* b2  = (const float*)d_in[7];
    const float* Wc1 = (const float*)d_in[8];
    const float* bc1 = (const float*)d_in[9];
    const float* Wc2 = (const float*)d_in[10];
    const float* bc2 = (const float*)d_in[11];
    const float* Wc3 = (const float*)d_in[12];
    const float* bc3 = (const float*)d_in[13];
    float* out = (float*)d_out;

    char* w = (char*)d_ws;
    size_t off = 0;
    auto alloc = [&](size_t bytes) -> char* {
        char* p = w + off;
        off += (bytes + 255) & ~(size_t)255;
        return p;
    };
    int* dego    = (int*)alloc((size_t)2 * N_NODES * 4);  // dego + degi contiguous for one memset
    int* degi    = dego + N_NODES;
    float* rso   = (float*)alloc((size_t)N_NODES * 4);
    float* rsi   = (float*)alloc((size_t)N_NODES * 4);
    int* rowp    = (int*)alloc((size_t)(N_NODES + 1) * 4);
    int* cursor  = (int*)alloc((size_t)N_NODES * 4);
    int* partial = (int*)alloc((size_t)N_NODES * 4);
    int* bsums   = (int*)alloc(1024);
    int* gstart  = (int*)alloc((size_t)(N_GRAPHS + 1) * 4);
    int* col     = (int*)alloc((size_t)N_EDGES * 4);
    float* R1    = (float*)alloc((size_t)N_NODES * HID * 4);  // agg1, later agg2
    float* R2    = (float*)alloc((size_t)N_NODES * HID * 4);  // h1s, later h2
    float* agg1 = R1;
    float* agg2 = R1;
    float* h1s  = R2;
    float* h2   = R2;

    (void)in_sizes; (void)n_in; (void)out_size; (void)ws_size;

    hipMemsetAsync(dego, 0, (size_t)2 * N_NODES * 4, stream);

    const int EB = (N_EDGES + 255) / 256;   // 6250
    const int NB = (N_NODES + 255) / 256;   // 391
    const int GB = (N_NODES * 64 + 255) / 256;  // one wave per node

    k_deg<<<EB, 256, 0, stream>>>(esrc, edst, dego, degi);
    k_rs<<<NB, 256, 0, stream>>>(dego, degi, rso, rsi);
    k_scan1<<<SCAN_NB, 256, 0, stream>>>(degi, partial, bsums);
    k_scan2<<<1, 128, 0, stream>>>(bsums);
    k_scan3<<<NB, 256, 0, stream>>>(partial, bsums, degi, rowp, cursor);
    k_scatter<<<EB, 256, 0, stream>>>(esrc, edst, cursor, col);
    k_gather64<<<GB, 256, 0, stream>>>((const float4*)x, rso, rowp, col, (float4*)agg1);
    k_mm<IN_DIM, true><<<(N_NODES + 31) / 32, 256, 0, stream>>>(agg1, W1, b1, rsi, rso, h1s);
    k_gather128<<<GB, 256, 0, stream>>>((const float4*)h1s, rowp, col, (float4*)agg2);
    k_mm<HID, false><<<(N_NODES + 31) / 32, 256, 0, stream>>>(agg2, W2, b2, rsi, rso, h2);
    k_bounds<<<3, 256, 0, stream>>>(gid, gstart);
    k_pool_mlp<<<N_GRAPHS, 128, 0, stream>>>(h2, gstart, Wc1, bc1, Wc2, bc2, Wc3, bc3, out);
}

// Round 3
// 501.955 us; speedup vs baseline: 1.4788x; 1.1739x over previous
//
#include <hip/hip_runtime.h>

#define N_NODES 100000
#define N_EDGES 1600000
#define IN_DIM 64
#define HID 128
#define N_GRAPHS 512
#define SCAN_NB 98   // ceil(100000/1024)
#define NBUCK 391    // ceil(100000/256) buckets of 256 dst nodes

// ---------------- degree count ----------------
__global__ __launch_bounds__(256) void k_deg(const int* __restrict__ src, const int* __restrict__ dst,
                                             int* __restrict__ dego, int* __restrict__ degi) {
    int i = blockIdx.x * 256 + threadIdx.x;
    if (i < N_EDGES) {
        atomicAdd(&dego[src[i]], 1);
        atomicAdd(&degi[dst[i]], 1);
    }
}

// ---------------- rsqrt of clipped degrees ----------------
__global__ __launch_bounds__(256) void k_rs(const int* __restrict__ dego, const int* __restrict__ degi,
                                            float* __restrict__ rso, float* __restrict__ rsi) {
    int i = blockIdx.x * 256 + threadIdx.x;
    if (i < N_NODES) {
        rso[i] = 1.0f / sqrtf(fmaxf((float)dego[i], 1.0f));
        rsi[i] = 1.0f / sqrtf(fmaxf((float)degi[i], 1.0f));
    }
}

// ---------------- scan (3 kernels) for CSR row_ptr over deg_in ----------------
__global__ __launch_bounds__(256) void k_scan1(const int* __restrict__ deg, int* __restrict__ partial,
                                               int* __restrict__ bsums) {
    __shared__ int lds[256];
    int t = threadIdx.x, b = blockIdx.x;
    int base = b * 1024 + t * 4;
    int v0 = 0, v1 = 0, v2 = 0, v3 = 0;
    if (base + 3 < N_NODES) {
        v0 = deg[base]; v1 = deg[base + 1]; v2 = deg[base + 2]; v3 = deg[base + 3];
    } else {
        if (base < N_NODES) v0 = deg[base];
        if (base + 1 < N_NODES) v1 = deg[base + 1];
        if (base + 2 < N_NODES) v2 = deg[base + 2];
        if (base + 3 < N_NODES) v3 = deg[base + 3];
    }
    v1 += v0; v2 += v1; v3 += v2;  // thread-local inclusive
    lds[t] = v3;
    __syncthreads();
    for (int off = 1; off < 256; off <<= 1) {
        int x = (t >= off) ? lds[t - off] : 0;
        __syncthreads();
        lds[t] += x;
        __syncthreads();
    }
    int prev = (t > 0) ? lds[t - 1] : 0;
    if (base < N_NODES) partial[base] = v0 + prev;
    if (base + 1 < N_NODES) partial[base + 1] = v1 + prev;
    if (base + 2 < N_NODES) partial[base + 2] = v2 + prev;
    if (base + 3 < N_NODES) partial[base + 3] = v3 + prev;
    if (t == 255) bsums[b] = lds[255];
}

__global__ __launch_bounds__(128) void k_scan2(int* __restrict__ bsums) {
    __shared__ int l[128];
    int t = threadIdx.x;
    l[t] = (t < SCAN_NB) ? bsums[t] : 0;
    __syncthreads();
    for (int off = 1; off < 128; off <<= 1) {
        int v = (t >= off) ? l[t - off] : 0;
        __syncthreads();
        l[t] += v;
        __syncthreads();
    }
    if (t < SCAN_NB) bsums[t] = (t > 0) ? l[t - 1] : 0;  // exclusive block offsets
}

__global__ __launch_bounds__(256) void k_scan3(const int* __restrict__ partial, const int* __restrict__ bsums,
                                               int* __restrict__ rowp) {
    int i = blockIdx.x * 256 + threadIdx.x;
    if (i >= N_NODES) return;
    rowp[i + 1] = partial[i] + bsums[i >> 10];
    if (i == 0) rowp[0] = 0;
}

// ---------------- init per-bucket cursors ----------------
__global__ __launch_bounds__(256) void k_binit(const int* __restrict__ rowp, int* __restrict__ bcur) {
    int b = blockIdx.x * 256 + threadIdx.x;
    if (b < NBUCK) bcur[b] = rowp[b * 256];
}

// ---------------- pass B: bin edges by dst>>8 into segment-contiguous (src,dst) pairs ----------------
__global__ __launch_bounds__(256) void k_bin(const int* __restrict__ src, const int* __restrict__ dst,
                                             int* __restrict__ bcur, int2* __restrict__ binned) {
    __shared__ int hist[NBUCK + 1];
    __shared__ int base[NBUCK + 1];
    const int t = threadIdx.x;
    const int e0 = blockIdx.x * 4096 + t * 16;  // this thread's 16 edges (contiguous)
    for (int i = t; i < NBUCK; i += 256) hist[i] = 0;
    __syncthreads();
    // count (dst only, int4 x4)
    if (e0 < N_EDGES) {
        const int4* d4 = (const int4*)(dst + e0);
#pragma unroll
        for (int u = 0; u < 4; ++u) {
            int4 d = d4[u];
            atomicAdd(&hist[d.x >> 8], 1);
            atomicAdd(&hist[d.y >> 8], 1);
            atomicAdd(&hist[d.z >> 8], 1);
            atomicAdd(&hist[d.w >> 8], 1);
        }
    }
    __syncthreads();
    // allocate global segment per bucket; reset hist for rank pass
    for (int i = t; i < NBUCK; i += 256) {
        int c = hist[i];
        base[i] = c ? atomicAdd(&bcur[i], c) : 0;
        hist[i] = 0;
    }
    __syncthreads();
    // scatter into segments
    if (e0 < N_EDGES) {
        const int4* d4 = (const int4*)(dst + e0);
        const int4* s4 = (const int4*)(src + e0);
#pragma unroll
        for (int u = 0; u < 4; ++u) {
            int4 d = d4[u];
            int4 s = s4[u];
            int bk, r;
            bk = d.x >> 8; r = atomicAdd(&hist[bk], 1); binned[base[bk] + r] = make_int2(s.x, d.x);
            bk = d.y >> 8; r = atomicAdd(&hist[bk], 1); binned[base[bk] + r] = make_int2(s.y, d.y);
            bk = d.z >> 8; r = atomicAdd(&hist[bk], 1); binned[base[bk] + r] = make_int2(s.z, d.z);
            bk = d.w >> 8; r = atomicAdd(&hist[bk], 1); binned[base[bk] + r] = make_int2(s.w, d.w);
        }
    }
}

// ---------------- pass C: within-bucket scatter to final CSR position ----------------
__global__ __launch_bounds__(256) void k_scat2(const int* __restrict__ rowp, const int2* __restrict__ binned,
                                               int* __restrict__ col) {
    const int b = blockIdx.x;
    const int n0 = b * 256;
    const int n1 = min(n0 + 256, N_NODES);
    const int t = threadIdx.x;
    __shared__ int cur[256];
    __shared__ int sb[2];
    if (t == 0) { sb[0] = rowp[n0]; sb[1] = rowp[n1]; }
    if (n0 + t < n1) cur[t] = rowp[n0 + t];
    __syncthreads();
    const int s = sb[0], e = sb[1];
    if (n0 + t < n1) cur[t] -= s;
    __syncthreads();
    for (int i = s + t; i < e; i += 256) {
        int2 p = binned[i];
        int r = atomicAdd(&cur[p.y - n0], 1);
        col[s + r] = p.x;
    }
}

// ---------------- gather-sum aggregation (64-dim), rso scale fused ----------------
__global__ __launch_bounds__(256) void k_gather64(const float4* __restrict__ x4, const float* __restrict__ rso,
                                                  const int* __restrict__ rowp, const int* __restrict__ col,
                                                  float4* __restrict__ agg4) {
    int wv = (blockIdx.x * 256 + threadIdx.x) >> 6;
    if (wv >= N_NODES) return;
    int lane = threadIdx.x & 63;
    int grp = lane >> 4, li = lane & 15;
    int s = rowp[wv], e = rowp[wv + 1];
    float ax = 0.f, ay = 0.f, az = 0.f, aw = 0.f;
    int i = s + grp;
    for (; i + 12 < e; i += 16) {
        int c0 = col[i], c1 = col[i + 4], c2 = col[i + 8], c3 = col[i + 12];
        float4 v0 = x4[c0 * 16 + li];
        float4 v1 = x4[c1 * 16 + li];
        float4 v2 = x4[c2 * 16 + li];
        float4 v3 = x4[c3 * 16 + li];
        float r0 = rso[c0], r1 = rso[c1], r2 = rso[c2], r3 = rso[c3];
        ax = fmaf(r0, v0.x, ax); ay = fmaf(r0, v0.y, ay); az = fmaf(r0, v0.z, az); aw = fmaf(r0, v0.w, aw);
        ax = fmaf(r1, v1.x, ax); ay = fmaf(r1, v1.y, ay); az = fmaf(r1, v1.z, az); aw = fmaf(r1, v1.w, aw);
        ax = fmaf(r2, v2.x, ax); ay = fmaf(r2, v2.y, ay); az = fmaf(r2, v2.z, az); aw = fmaf(r2, v2.w, aw);
        ax = fmaf(r3, v3.x, ax); ay = fmaf(r3, v3.y, ay); az = fmaf(r3, v3.z, az); aw = fmaf(r3, v3.w, aw);
    }
    for (; i < e; i += 4) {
        int c = col[i];
        float4 v = x4[c * 16 + li];
        float r = rso[c];
        ax = fmaf(r, v.x, ax); ay = fmaf(r, v.y, ay); az = fmaf(r, v.z, az); aw = fmaf(r, v.w, aw);
    }
    ax += __shfl_xor(ax, 16, 64); ay += __shfl_xor(ay, 16, 64);
    az += __shfl_xor(az, 16, 64); aw += __shfl_xor(aw, 16, 64);
    ax += __shfl_xor(ax, 32, 64); ay += __shfl_xor(ay, 32, 64);
    az += __shfl_xor(az, 32, 64); aw += __shfl_xor(aw, 32, 64);
    if (lane < 16) {
        float4 o; o.x = ax; o.y = ay; o.z = az; o.w = aw;
        agg4[wv * 16 + li] = o;
    }
}

// ---------------- gather-sum aggregation (128-dim) ----------------
__global__ __launch_bounds__(256) void k_gather128(const float4* __restrict__ h4, const int* __restrict__ rowp,
                                                   const int* __restrict__ col, float4* __restrict__ agg4) {
    int wv = (blockIdx.x * 256 + threadIdx.x) >> 6;
    if (wv >= N_NODES) return;
    int lane = threadIdx.x & 63;
    int grp = lane >> 5, li = lane & 31;
    int s = rowp[wv], e = rowp[wv + 1];
    float ax = 0.f, ay = 0.f, az = 0.f, aw = 0.f;
    int i = s + grp;
    for (; i + 6 < e; i += 8) {
        int c0 = col[i], c1 = col[i + 2], c2 = col[i + 4], c3 = col[i + 6];
        float4 v0 = h4[c0 * 32 + li];
        float4 v1 = h4[c1 * 32 + li];
        float4 v2 = h4[c2 * 32 + li];
        float4 v3 = h4[c3 * 32 + li];
        ax += v0.x + v1.x + v2.x + v3.x;
        ay += v0.y + v1.y + v2.y + v3.y;
        az += v0.z + v1.z + v2.z + v3.z;
        aw += v0.w + v1.w + v2.w + v3.w;
    }
    for (; i < e; i += 2) {
        float4 v = h4[col[i] * 32 + li];
        ax += v.x; ay += v.y; az += v.z; aw += v.w;
    }
    ax += __shfl_xor(ax, 32, 64); ay += __shfl_xor(ay, 32, 64);
    az += __shfl_xor(az, 32, 64); aw += __shfl_xor(aw, 32, 64);
    if (lane < 32) {
        float4 o; o.x = ax; o.y = ay; o.z = az; o.w = aw;
        agg4[wv * 32 + li] = o;
    }
}

// ---------------- tiled f32 matmul: out = epilogue(A @ W) ----------------
template <int K, bool SCALE_OUT>
__global__ __launch_bounds__(256) void k_mm(const float* __restrict__ A, const float* __restrict__ W,
                                            const float* __restrict__ bias, const float* __restrict__ rsi,
                                            const float* __restrict__ rso, float* __restrict__ out) {
    __shared__ float WL[32 * 128];   // one 32-row chunk of W
    __shared__ float aL[32][33];     // 32 nodes x 32 k (padded)
    const int t = threadIdx.x;
    const int jq = t & 31;           // covers columns jq*4 .. jq*4+3
    const int ns = t >> 5;           // node group: nodes ns*4 .. ns*4+3
    const int n0 = blockIdx.x * 32;
    float acc[4][4] = {};
    for (int kc = 0; kc < K; kc += 32) {
        const float4* Wg = (const float4*)(W + kc * 128);
        float4* WL4 = (float4*)WL;
#pragma unroll
        for (int u = 0; u < 4; ++u) WL4[t + 256 * u] = Wg[t + 256 * u];
        {
            int r = t >> 3, q = t & 7;
            int node = n0 + r;
            float4 v = make_float4(0.f, 0.f, 0.f, 0.f);
            if (node < N_NODES) v = *(const float4*)(A + node * K + kc + q * 4);
            aL[r][q * 4 + 0] = v.x; aL[r][q * 4 + 1] = v.y;
            aL[r][q * 4 + 2] = v.z; aL[r][q * 4 + 3] = v.w;
        }
        __syncthreads();
#pragma unroll
        for (int k = 0; k < 32; ++k) {
            float4 wv = ((const float4*)WL)[k * 32 + jq];
#pragma unroll
            for (int i = 0; i < 4; ++i) {
                float av = aL[ns * 4 + i][k];
                acc[i][0] += av * wv.x; acc[i][1] += av * wv.y;
                acc[i][2] += av * wv.z; acc[i][3] += av * wv.w;
            }
        }
        __syncthreads();
    }
#pragma unroll
    for (int i = 0; i < 4; ++i) {
        int node = n0 + ns * 4 + i;
        if (node >= N_NODES) continue;
        float ri = rsi[node];
        float ro = SCALE_OUT ? rso[node] : 1.0f;
        float4 bj = ((const float4*)bias)[jq];
        float4 o;
        o.x = fmaxf(acc[i][0] * ri + bj.x, 0.f) * ro;
        o.y = fmaxf(acc[i][1] * ri + bj.y, 0.f) * ro;
        o.z = fmaxf(acc[i][2] * ri + bj.z, 0.f) * ro;
        o.w = fmaxf(acc[i][3] * ri + bj.w, 0.f) * ro;
        *(float4*)(out + node * HID + jq * 4) = o;
    }
}

// ---------------- per-graph node ranges (graph_ids is sorted) ----------------
__global__ __launch_bounds__(256) void k_bounds(const int* __restrict__ gid, int* __restrict__ gstart) {
    int g = blockIdx.x * 256 + threadIdx.x;
    if (g > N_GRAPHS) return;
    int lo = 0, hi = N_NODES;
    while (lo < hi) {
        int mid = (lo + hi) >> 1;
        if (gid[mid] < g) lo = mid + 1; else hi = mid;
    }
    gstart[g] = lo;
}

// ---------------- mean-pool + 3-layer MLP head, one block per graph ----------------
__global__ __launch_bounds__(128) void k_pool_mlp(const float* __restrict__ h2, const int* __restrict__ gstart,
                                                  const float* __restrict__ Wc1, const float* __restrict__ bc1,
                                                  const float* __restrict__ Wc2, const float* __restrict__ bc2,
                                                  const float* __restrict__ Wc3, const float* __restrict__ bc3,
                                                  float* __restrict__ out) {
    int g = blockIdx.x, t = threadIdx.x;
    int s = gstart[g], e = gstart[g + 1];
    float acc = 0.f;
    for (int n = s; n < e; ++n) acc += h2[n * HID + t];
    float cnt = fmaxf((float)(e - s), 1.0f);
    __shared__ float buf[HID];
    __shared__ float red[2];
    buf[t] = acc / cnt;
    __syncthreads();
    float a = bc1[t];
#pragma unroll 8
    for (int k = 0; k < HID; ++k) a += buf[k] * Wc1[k * HID + t];
    a = fmaxf(a, 0.f);
    __syncthreads();
    buf[t] = a;
    __syncthreads();
    float b = bc2[t];
#pragma unroll 8
    for (int k = 0; k < HID; ++k) b += buf[k] * Wc2[k * HID + t];
    b = fmaxf(b, 0.f);
    float p = b * Wc3[t];
    for (int off = 32; off > 0; off >>= 1) p += __shfl_down(p, off, 64);
    if ((t & 63) == 0) red[t >> 6] = p;
    __syncthreads();
    if (t == 0) out[g] = red[0] + red[1] + bc3[0];
}

extern "C" void kernel_launch(void* const* d_in, const int* in_sizes, int n_in,
                              void* d_out, int out_size, void* d_ws, size_t ws_size,
                              hipStream_t stream) {
    const float* x   = (const float*)d_in[0];
    const int* esrc  = (const int*)d_in[1];
    const int* edst  = (const int*)d_in[2];
    const int* gid   = (const int*)d_in[3];
    const float* W1  = (const float*)d_in[4];
    const float* b1  = (const float*)d_in[5];
    const float* W2  = (const float*)d_in[6];
    const float* b2  = (const float*)d_in[7];
    const float* Wc1 = (const float*)d_in[8];
    const float* bc1 = (const float*)d_in[9];
    const float* Wc2 = (const float*)d_in[10];
    const float* bc2 = (const float*)d_in[11];
    const float* Wc3 = (const float*)d_in[12];
    const float* bc3 = (const float*)d_in[13];
    float* out = (float*)d_out;

    char* w = (char*)d_ws;
    size_t off = 0;
    auto alloc = [&](size_t bytes) -> char* {
        char* p = w + off;
        off += (bytes + 255) & ~(size_t)255;
        return p;
    };
    int* dego    = (int*)alloc((size_t)2 * N_NODES * 4);  // dego + degi contiguous for one memset
    int* degi    = dego + N_NODES;
    float* rso   = (float*)alloc((size_t)N_NODES * 4);
    float* rsi   = (float*)alloc((size_t)N_NODES * 4);
    int* rowp    = (int*)alloc((size_t)(N_NODES + 1) * 4);
    int* partial = (int*)alloc((size_t)N_NODES * 4);
    int* bsums   = (int*)alloc(1024);
    int* bcur    = (int*)alloc((size_t)NBUCK * 4);
    int* gstart  = (int*)alloc((size_t)(N_GRAPHS + 1) * 4);
    int* col     = (int*)alloc((size_t)N_EDGES * 4);
    float* R1    = (float*)alloc((size_t)N_NODES * HID * 4);  // binned | agg1 | agg2
    float* R2    = (float*)alloc((size_t)N_NODES * HID * 4);  // h1s, later h2
    int2* binned = (int2*)R1;   // 12.8 MB, dead before agg1 is written
    float* agg1 = R1;
    float* agg2 = R1;
    float* h1s  = R2;
    float* h2   = R2;

    (void)in_sizes; (void)n_in; (void)out_size; (void)ws_size;

    hipMemsetAsync(dego, 0, (size_t)2 * N_NODES * 4, stream);

    const int EB = (N_EDGES + 255) / 256;       // 6250
    const int NB = (N_NODES + 255) / 256;       // 391
    const int BB = (N_EDGES + 4095) / 4096;     // 391 bin blocks
    const int GB = (N_NODES * 64 + 255) / 256;  // one wave per node

    k_deg<<<EB, 256, 0, stream>>>(esrc, edst, dego, degi);
    k_rs<<<NB, 256, 0, stream>>>(dego, degi, rso, rsi);
    k_scan1<<<SCAN_NB, 256, 0, stream>>>(degi, partial, bsums);
    k_scan2<<<1, 128, 0, stream>>>(bsums);
    k_scan3<<<NB, 256, 0, stream>>>(partial, bsums, rowp);
    k_binit<<<2, 256, 0, stream>>>(rowp, bcur);
    k_bin<<<BB, 256, 0, stream>>>(esrc, edst, bcur, binned);
    k_scat2<<<NBUCK, 256, 0, stream>>>(rowp, binned, col);
    k_gather64<<<GB, 256, 0, stream>>>((const float4*)x, rso, rowp, col, (float4*)agg1);
    k_mm<IN_DIM, true><<<(N_NODES + 31) / 32, 256, 0, stream>>>(agg1, W1, b1, rsi, rso, h1s);
    k_gather128<<<GB, 256, 0, stream>>>((const float4*)h1s, rowp, col, (float4*)agg2);
    k_mm<HID, false><<<(N_NODES + 31) / 32, 256, 0, stream>>>(agg2, W2, b2, rsi, rso, h2);
    k_bounds<<<3, 256, 0, stream>>>(gid, gstart);
    k_pool_mlp<<<N_GRAPHS, 128, 0, stream>>>(h2, gstart, Wc1, bc1, Wc2, bc2, Wc3, bc3, out);
}

// Round 4
// 415.239 us; speedup vs baseline: 1.7876x; 1.2088x over previous
//
#include <hip/hip_runtime.h>

#define N_NODES 100000
#define N_EDGES 1600000
#define IN_DIM 64
#define HID 128
#define N_GRAPHS 512
#define NBUCK 391    // ceil(100000/256) buckets of 256 nodes

// ---------------- pass A: per-block LDS histogram of src/dst buckets ----------------
__global__ __launch_bounds__(256) void k_bhist(const int* __restrict__ src, const int* __restrict__ dst,
                                               int* __restrict__ dcnt, int* __restrict__ scnt) {
    __shared__ int hd[NBUCK];
    __shared__ int hs[NBUCK];
    const int t = threadIdx.x;
    const int e0 = blockIdx.x * 4096 + t * 16;
    for (int i = t; i < NBUCK; i += 256) { hd[i] = 0; hs[i] = 0; }
    __syncthreads();
    if (e0 < N_EDGES) {
        const int4* d4 = (const int4*)(dst + e0);
        const int4* s4 = (const int4*)(src + e0);
#pragma unroll
        for (int u = 0; u < 4; ++u) {
            int4 d = d4[u], s = s4[u];
            atomicAdd(&hd[d.x >> 8], 1); atomicAdd(&hd[d.y >> 8], 1);
            atomicAdd(&hd[d.z >> 8], 1); atomicAdd(&hd[d.w >> 8], 1);
            atomicAdd(&hs[s.x >> 8], 1); atomicAdd(&hs[s.y >> 8], 1);
            atomicAdd(&hs[s.z >> 8], 1); atomicAdd(&hs[s.w >> 8], 1);
        }
    }
    __syncthreads();
    for (int i = t; i < NBUCK; i += 256) {
        if (hd[i]) atomicAdd(&dcnt[i], hd[i]);
        if (hs[i]) atomicAdd(&scnt[i], hs[i]);
    }
}

// ---------------- scan bucket counts -> bases + cursors (one block) ----------------
__global__ __launch_bounds__(512) void k_bscan(const int* __restrict__ dcnt, const int* __restrict__ scnt,
                                               int* __restrict__ dbase, int* __restrict__ sbase,
                                               int* __restrict__ dcur, int* __restrict__ scur) {
    __shared__ int l[512];
    const int t = threadIdx.x;
    // dst
    int v = (t < NBUCK) ? dcnt[t] : 0;
    l[t] = v;
    __syncthreads();
    for (int off = 1; off < 512; off <<= 1) {
        int x = (t >= off) ? l[t - off] : 0;
        __syncthreads();
        l[t] += x;
        __syncthreads();
    }
    if (t < NBUCK) {
        int excl = l[t] - v;
        dbase[t] = excl; dcur[t] = excl;
    }
    if (t == NBUCK - 1) dbase[NBUCK] = l[t];
    __syncthreads();
    // src
    v = (t < NBUCK) ? scnt[t] : 0;
    l[t] = v;
    __syncthreads();
    for (int off = 1; off < 512; off <<= 1) {
        int x = (t >= off) ? l[t - off] : 0;
        __syncthreads();
        l[t] += x;
        __syncthreads();
    }
    if (t < NBUCK) {
        int excl = l[t] - v;
        sbase[t] = excl; scur[t] = excl;
    }
    if (t == NBUCK - 1) sbase[NBUCK] = l[t];
}

// ---------------- pass B: bin (src,dst) pairs by dst bucket ----------------
__global__ __launch_bounds__(256) void k_bin_dst(const int* __restrict__ src, const int* __restrict__ dst,
                                                 int* __restrict__ dcur, int2* __restrict__ binned) {
    __shared__ int hist[NBUCK];
    __shared__ int base[NBUCK];
    const int t = threadIdx.x;
    const int e0 = blockIdx.x * 4096 + t * 16;
    for (int i = t; i < NBUCK; i += 256) hist[i] = 0;
    __syncthreads();
    if (e0 < N_EDGES) {
        const int4* d4 = (const int4*)(dst + e0);
#pragma unroll
        for (int u = 0; u < 4; ++u) {
            int4 d = d4[u];
            atomicAdd(&hist[d.x >> 8], 1); atomicAdd(&hist[d.y >> 8], 1);
            atomicAdd(&hist[d.z >> 8], 1); atomicAdd(&hist[d.w >> 8], 1);
        }
    }
    __syncthreads();
    for (int i = t; i < NBUCK; i += 256) {
        int c = hist[i];
        base[i] = c ? atomicAdd(&dcur[i], c) : 0;
        hist[i] = 0;
    }
    __syncthreads();
    if (e0 < N_EDGES) {
        const int4* d4 = (const int4*)(dst + e0);
        const int4* s4 = (const int4*)(src + e0);
#pragma unroll
        for (int u = 0; u < 4; ++u) {
            int4 d = d4[u];
            int4 s = s4[u];
            int bk, r;
            bk = d.x >> 8; r = atomicAdd(&hist[bk], 1); binned[base[bk] + r] = make_int2(s.x, d.x);
            bk = d.y >> 8; r = atomicAdd(&hist[bk], 1); binned[base[bk] + r] = make_int2(s.y, d.y);
            bk = d.z >> 8; r = atomicAdd(&hist[bk], 1); binned[base[bk] + r] = make_int2(s.z, d.z);
            bk = d.w >> 8; r = atomicAdd(&hist[bk], 1); binned[base[bk] + r] = make_int2(s.w, d.w);
        }
    }
}

// ---------------- pass B': bin src ids by src bucket (for out-degree) ----------------
__global__ __launch_bounds__(256) void k_bin_src(const int* __restrict__ src,
                                                 int* __restrict__ scur, int* __restrict__ binnedS) {
    __shared__ int hist[NBUCK];
    __shared__ int base[NBUCK];
    const int t = threadIdx.x;
    const int e0 = blockIdx.x * 4096 + t * 16;
    for (int i = t; i < NBUCK; i += 256) hist[i] = 0;
    __syncthreads();
    if (e0 < N_EDGES) {
        const int4* s4 = (const int4*)(src + e0);
#pragma unroll
        for (int u = 0; u < 4; ++u) {
            int4 s = s4[u];
            atomicAdd(&hist[s.x >> 8], 1); atomicAdd(&hist[s.y >> 8], 1);
            atomicAdd(&hist[s.z >> 8], 1); atomicAdd(&hist[s.w >> 8], 1);
        }
    }
    __syncthreads();
    for (int i = t; i < NBUCK; i += 256) {
        int c = hist[i];
        base[i] = c ? atomicAdd(&scur[i], c) : 0;
        hist[i] = 0;
    }
    __syncthreads();
    if (e0 < N_EDGES) {
        const int4* s4 = (const int4*)(src + e0);
#pragma unroll
        for (int u = 0; u < 4; ++u) {
            int4 s = s4[u];
            int bk, r;
            bk = s.x >> 8; r = atomicAdd(&hist[bk], 1); binnedS[base[bk] + r] = s.x;
            bk = s.y >> 8; r = atomicAdd(&hist[bk], 1); binnedS[base[bk] + r] = s.y;
            bk = s.z >> 8; r = atomicAdd(&hist[bk], 1); binnedS[base[bk] + r] = s.z;
            bk = s.w >> 8; r = atomicAdd(&hist[bk], 1); binnedS[base[bk] + r] = s.w;
        }
    }
}

// ---------------- pass C': per-bucket out-degree count -> rso ----------------
__global__ __launch_bounds__(256) void k_cnt_src(const int* __restrict__ sbase, const int* __restrict__ binnedS,
                                                 float* __restrict__ rso) {
    const int b = blockIdx.x;
    const int n0 = b * 256;
    const int t = threadIdx.x;
    __shared__ int cnt[256];
    __shared__ int sb[2];
    if (t < 2) sb[t] = sbase[b + t];
    cnt[t] = 0;
    __syncthreads();
    const int s = sb[0], e = sb[1];
    for (int i = s + t; i < e; i += 256) atomicAdd(&cnt[binnedS[i] - n0], 1);
    __syncthreads();
    if (n0 + t < N_NODES) rso[n0 + t] = 1.0f / sqrtf(fmaxf((float)cnt[t], 1.0f));
}

// ---------------- pass C: per-bucket in-degree count + scan + CSR scatter ----------------
__global__ __launch_bounds__(256) void k_build_dst(const int* __restrict__ dbase, const int2* __restrict__ binned,
                                                   int* __restrict__ rowp, float* __restrict__ rsi,
                                                   int* __restrict__ col) {
    const int b = blockIdx.x;
    const int n0 = b * 256;
    const int t = threadIdx.x;
    __shared__ int cnt[256];
    __shared__ int scn[256];
    __shared__ int cur[256];
    __shared__ int sb[2];
    if (t < 2) sb[t] = dbase[b + t];
    cnt[t] = 0;
    __syncthreads();
    const int s = sb[0], e = sb[1];
    for (int i = s + t; i < e; i += 256) atomicAdd(&cnt[binned[i].y - n0], 1);
    __syncthreads();
    const int c = cnt[t];
    scn[t] = c;
    __syncthreads();
    for (int off = 1; off < 256; off <<= 1) {
        int v = (t >= off) ? scn[t - off] : 0;
        __syncthreads();
        scn[t] += v;
        __syncthreads();
    }
    const int excl = scn[t] - c;
    cur[t] = excl;
    if (n0 + t < N_NODES) {
        rowp[n0 + t] = s + excl;
        rsi[n0 + t] = 1.0f / sqrtf(fmaxf((float)c, 1.0f));
    }
    if (b == NBUCK - 1 && t == 0) rowp[N_NODES] = e;
    __syncthreads();
    for (int i = s + t; i < e; i += 256) {
        int2 p = binned[i];
        int r = atomicAdd(&cur[p.y - n0], 1);
        col[s + r] = p.x;
    }
}

// ---------------- gather-sum aggregation (64-dim), rso scale fused ----------------
__global__ __launch_bounds__(256) void k_gather64(const float4* __restrict__ x4, const float* __restrict__ rso,
                                                  const int* __restrict__ rowp, const int* __restrict__ col,
                                                  float4* __restrict__ agg4) {
    int wv = (blockIdx.x * 256 + threadIdx.x) >> 6;
    if (wv >= N_NODES) return;
    int lane = threadIdx.x & 63;
    int grp = lane >> 4, li = lane & 15;
    int s = rowp[wv], e = rowp[wv + 1];
    float ax = 0.f, ay = 0.f, az = 0.f, aw = 0.f;
    int i = s + grp;
    for (; i + 12 < e; i += 16) {
        int c0 = col[i], c1 = col[i + 4], c2 = col[i + 8], c3 = col[i + 12];
        float4 v0 = x4[c0 * 16 + li];
        float4 v1 = x4[c1 * 16 + li];
        float4 v2 = x4[c2 * 16 + li];
        float4 v3 = x4[c3 * 16 + li];
        float r0 = rso[c0], r1 = rso[c1], r2 = rso[c2], r3 = rso[c3];
        ax = fmaf(r0, v0.x, ax); ay = fmaf(r0, v0.y, ay); az = fmaf(r0, v0.z, az); aw = fmaf(r0, v0.w, aw);
        ax = fmaf(r1, v1.x, ax); ay = fmaf(r1, v1.y, ay); az = fmaf(r1, v1.z, az); aw = fmaf(r1, v1.w, aw);
        ax = fmaf(r2, v2.x, ax); ay = fmaf(r2, v2.y, ay); az = fmaf(r2, v2.z, az); aw = fmaf(r2, v2.w, aw);
        ax = fmaf(r3, v3.x, ax); ay = fmaf(r3, v3.y, ay); az = fmaf(r3, v3.z, az); aw = fmaf(r3, v3.w, aw);
    }
    for (; i < e; i += 4) {
        int c = col[i];
        float4 v = x4[c * 16 + li];
        float r = rso[c];
        ax = fmaf(r, v.x, ax); ay = fmaf(r, v.y, ay); az = fmaf(r, v.z, az); aw = fmaf(r, v.w, aw);
    }
    ax += __shfl_xor(ax, 16, 64); ay += __shfl_xor(ay, 16, 64);
    az += __shfl_xor(az, 16, 64); aw += __shfl_xor(aw, 16, 64);
    ax += __shfl_xor(ax, 32, 64); ay += __shfl_xor(ay, 32, 64);
    az += __shfl_xor(az, 32, 64); aw += __shfl_xor(aw, 32, 64);
    if (lane < 16) {
        float4 o; o.x = ax; o.y = ay; o.z = az; o.w = aw;
        agg4[wv * 16 + li] = o;
    }
}

// ---------------- gather-sum aggregation (128-dim) ----------------
__global__ __launch_bounds__(256) void k_gather128(const float4* __restrict__ h4, const int* __restrict__ rowp,
                                                   const int* __restrict__ col, float4* __restrict__ agg4) {
    int wv = (blockIdx.x * 256 + threadIdx.x) >> 6;
    if (wv >= N_NODES) return;
    int lane = threadIdx.x & 63;
    int grp = lane >> 5, li = lane & 31;
    int s = rowp[wv], e = rowp[wv + 1];
    float ax = 0.f, ay = 0.f, az = 0.f, aw = 0.f;
    int i = s + grp;
    for (; i + 6 < e; i += 8) {
        int c0 = col[i], c1 = col[i + 2], c2 = col[i + 4], c3 = col[i + 6];
        float4 v0 = h4[c0 * 32 + li];
        float4 v1 = h4[c1 * 32 + li];
        float4 v2 = h4[c2 * 32 + li];
        float4 v3 = h4[c3 * 32 + li];
        ax += v0.x + v1.x + v2.x + v3.x;
        ay += v0.y + v1.y + v2.y + v3.y;
        az += v0.z + v1.z + v2.z + v3.z;
        aw += v0.w + v1.w + v2.w + v3.w;
    }
    for (; i < e; i += 2) {
        float4 v = h4[col[i] * 32 + li];
        ax += v.x; ay += v.y; az += v.z; aw += v.w;
    }
    ax += __shfl_xor(ax, 32, 64); ay += __shfl_xor(ay, 32, 64);
    az += __shfl_xor(az, 32, 64); aw += __shfl_xor(aw, 32, 64);
    if (lane < 32) {
        float4 o; o.x = ax; o.y = ay; o.z = az; o.w = aw;
        agg4[wv * 32 + li] = o;
    }
}

// ---------------- tiled f32 matmul: out = epilogue(A @ W) ----------------
template <int K, bool SCALE_OUT>
__global__ __launch_bounds__(256) void k_mm(const float* __restrict__ A, const float* __restrict__ W,
                                            const float* __restrict__ bias, const float* __restrict__ rsi,
                                            const float* __restrict__ rso, float* __restrict__ out) {
    __shared__ float WL[32 * 128];   // one 32-row chunk of W
    __shared__ float aL[32][33];     // 32 nodes x 32 k (padded)
    const int t = threadIdx.x;
    const int jq = t & 31;           // covers columns jq*4 .. jq*4+3
    const int ns = t >> 5;           // node group: nodes ns*4 .. ns*4+3
    const int n0 = blockIdx.x * 32;
    float acc[4][4] = {};
    for (int kc = 0; kc < K; kc += 32) {
        const float4* Wg = (const float4*)(W + kc * 128);
        float4* WL4 = (float4*)WL;
#pragma unroll
        for (int u = 0; u < 4; ++u) WL4[t + 256 * u] = Wg[t + 256 * u];
        {
            int r = t >> 3, q = t & 7;
            int node = n0 + r;
            float4 v = make_float4(0.f, 0.f, 0.f, 0.f);
            if (node < N_NODES) v = *(const float4*)(A + node * K + kc + q * 4);
            aL[r][q * 4 + 0] = v.x; aL[r][q * 4 + 1] = v.y;
            aL[r][q * 4 + 2] = v.z; aL[r][q * 4 + 3] = v.w;
        }
        __syncthreads();
#pragma unroll
        for (int k = 0; k < 32; ++k) {
            float4 wv = ((const float4*)WL)[k * 32 + jq];
#pragma unroll
            for (int i = 0; i < 4; ++i) {
                float av = aL[ns * 4 + i][k];
                acc[i][0] += av * wv.x; acc[i][1] += av * wv.y;
                acc[i][2] += av * wv.z; acc[i][3] += av * wv.w;
            }
        }
        __syncthreads();
    }
#pragma unroll
    for (int i = 0; i < 4; ++i) {
        int node = n0 + ns * 4 + i;
        if (node >= N_NODES) continue;
        float ri = rsi[node];
        float ro = SCALE_OUT ? rso[node] : 1.0f;
        float4 bj = ((const float4*)bias)[jq];
        float4 o;
        o.x = fmaxf(acc[i][0] * ri + bj.x, 0.f) * ro;
        o.y = fmaxf(acc[i][1] * ri + bj.y, 0.f) * ro;
        o.z = fmaxf(acc[i][2] * ri + bj.z, 0.f) * ro;
        o.w = fmaxf(acc[i][3] * ri + bj.w, 0.f) * ro;
        *(float4*)(out + node * HID + jq * 4) = o;
    }
}

// ---------------- per-graph node ranges (graph_ids is sorted) ----------------
__global__ __launch_bounds__(256) void k_bounds(const int* __restrict__ gid, int* __restrict__ gstart) {
    int g = blockIdx.x * 256 + threadIdx.x;
    if (g > N_GRAPHS) return;
    int lo = 0, hi = N_NODES;
    while (lo < hi) {
        int mid = (lo + hi) >> 1;
        if (gid[mid] < g) lo = mid + 1; else hi = mid;
    }
    gstart[g] = lo;
}

// ---------------- mean-pool + 3-layer MLP head, one block per graph ----------------
__global__ __launch_bounds__(128) void k_pool_mlp(const float* __restrict__ h2, const int* __restrict__ gstart,
                                                  const float* __restrict__ Wc1, const float* __restrict__ bc1,
                                                  const float* __restrict__ Wc2, const float* __restrict__ bc2,
                                                  const float* __restrict__ Wc3, const float* __restrict__ bc3,
                                                  float* __restrict__ out) {
    int g = blockIdx.x, t = threadIdx.x;
    int s = gstart[g], e = gstart[g + 1];
    float acc = 0.f;
    for (int n = s; n < e; ++n) acc += h2[n * HID + t];
    float cnt = fmaxf((float)(e - s), 1.0f);
    __shared__ float buf[HID];
    __shared__ float red[2];
    buf[t] = acc / cnt;
    __syncthreads();
    float a = bc1[t];
#pragma unroll 8
    for (int k = 0; k < HID; ++k) a += buf[k] * Wc1[k * HID + t];
    a = fmaxf(a, 0.f);
    __syncthreads();
    buf[t] = a;
    __syncthreads();
    float b = bc2[t];
#pragma unroll 8
    for (int k = 0; k < HID; ++k) b += buf[k] * Wc2[k * HID + t];
    b = fmaxf(b, 0.f);
    float p = b * Wc3[t];
    for (int off = 32; off > 0; off >>= 1) p += __shfl_down(p, off, 64);
    if ((t & 63) == 0) red[t >> 6] = p;
    __syncthreads();
    if (t == 0) out[g] = red[0] + red[1] + bc3[0];
}

extern "C" void kernel_launch(void* const* d_in, const int* in_sizes, int n_in,
                              void* d_out, int out_size, void* d_ws, size_t ws_size,
                              hipStream_t stream) {
    const float* x   = (const float*)d_in[0];
    const int* esrc  = (const int*)d_in[1];
    const int* edst  = (const int*)d_in[2];
    const int* gid   = (const int*)d_in[3];
    const float* W1  = (const float*)d_in[4];
    const float* b1  = (const float*)d_in[5];
    const float* W2  = (const float*)d_in[6];
    const float* b2  = (const float*)d_in[7];
    const float* Wc1 = (const float*)d_in[8];
    const float* bc1 = (const float*)d_in[9];
    const float* Wc2 = (const float*)d_in[10];
    const float* bc2 = (const float*)d_in[11];
    const float* Wc3 = (const float*)d_in[12];
    const float* bc3 = (const float*)d_in[13];
    float* out = (float*)d_out;

    char* w = (char*)d_ws;
    size_t off = 0;
    auto alloc = [&](size_t bytes) -> char* {
        char* p = w + off;
        off += (bytes + 255) & ~(size_t)255;
        return p;
    };
    int* dcnt   = (int*)alloc((size_t)2 * (NBUCK + 1) * 4);  // dcnt+scnt contiguous (one memset)
    int* scnt   = dcnt + (NBUCK + 1);
    int* dbase  = (int*)alloc((size_t)(NBUCK + 1) * 4);
    int* sbase  = (int*)alloc((size_t)(NBUCK + 1) * 4);
    int* dcur   = (int*)alloc((size_t)NBUCK * 4);
    int* scur   = (int*)alloc((size_t)NBUCK * 4);
    float* rso  = (float*)alloc((size_t)N_NODES * 4);
    float* rsi  = (float*)alloc((size_t)N_NODES * 4);
    int* rowp   = (int*)alloc((size_t)(N_NODES + 1) * 4);
    int* gstart = (int*)alloc((size_t)(N_GRAPHS + 1) * 4);
    int* col    = (int*)alloc((size_t)N_EDGES * 4);
    float* R1   = (float*)alloc((size_t)N_NODES * HID * 4);  // binnedD | binnedS | agg1 | agg2
    float* R2   = (float*)alloc((size_t)N_NODES * HID * 4);  // h1s, later h2
    int2* binnedD = (int2*)R1;                         // 12.8 MB
    int*  binnedS = (int*)(R1 + (size_t)N_EDGES * 2);  // 6.4 MB, after binnedD
    float* agg1 = R1;
    float* agg2 = R1;
    float* h1s  = R2;
    float* h2   = R2;

    (void)in_sizes; (void)n_in; (void)out_size; (void)ws_size;

    hipMemsetAsync(dcnt, 0, (size_t)2 * (NBUCK + 1) * 4, stream);

    const int BB = (N_EDGES + 4095) / 4096;     // 391 edge blocks
    const int GB = (N_NODES * 64 + 255) / 256;  // one wave per node

    k_bhist<<<BB, 256, 0, stream>>>(esrc, edst, dcnt, scnt);
    k_bscan<<<1, 512, 0, stream>>>(dcnt, scnt, dbase, sbase, dcur, scur);
    k_bin_dst<<<BB, 256, 0, stream>>>(esrc, edst, dcur, binnedD);
    k_bin_src<<<BB, 256, 0, stream>>>(esrc, scur, binnedS);
    k_cnt_src<<<NBUCK, 256, 0, stream>>>(sbase, binnedS, rso);
    k_build_dst<<<NBUCK, 256, 0, stream>>>(dbase, binnedD, rowp, rsi, col);
    k_gather64<<<GB, 256, 0, stream>>>((const float4*)x, rso, rowp, col, (float4*)agg1);
    k_mm<IN_DIM, true><<<(N_NODES + 31) / 32, 256, 0, stream>>>(agg1, W1, b1, rsi, rso, h1s);
    k_gather128<<<GB, 256, 0, stream>>>((const float4*)h1s, rowp, col, (float4*)agg2);
    k_mm<HID, false><<<(N_NODES + 31) / 32, 256, 0, stream>>>(agg2, W2, b2, rsi, rso, h2);
    k_bounds<<<3, 256, 0, stream>>>(gid, gstart);
    k_pool_mlp<<<N_GRAPHS, 128, 0, stream>>>(h2, gstart, Wc1, bc1, Wc2, bc2, Wc3, bc3, out);
}